// Round 2
// baseline (1000.828 us; speedup 1.0000x reference)
//
#include <hip/hip_runtime.h>

// GraphSAGE 3-layer, fp32.
// Linearity: segsum(Wm@concat(nf[src],ef)) == Wm_n@segsum(nf[src]) + Wm_e@segsum(ef) + deg*bm
// R3: on-device CSR + atomic-free gather aggregations (912 us).
// R4: GEMM rewrite — 128x64 tile, 8x4/thread, K-step 16, register prefetch
// (next tile's global loads issue before compute; vmcnt drains under FMA).
// R5 (this): identical resubmit — R4 bench died to container infra, no data.

#define NN 50000
#define NE 800000
#define NIN 64
#define EDIM_ 64
#define HID_ 152
#define NOUT 64
#define PADN 50176   // 49 * 1024, scan-friendly padding of NN

// ---------------- histogram: integer in-degree ----------------
__global__ __launch_bounds__(256) void hist_kernel(const int* __restrict__ dst,
                                                   int* __restrict__ ideg) {
    int e = blockIdx.x * 256 + threadIdx.x;
    if (e < NE) atomicAdd(&ideg[dst[e]], 1);
}

// ---------------- exclusive scan, 3 kernels ----------------
__global__ __launch_bounds__(256) void scan1_kernel(const int* __restrict__ in,
                                                    int* __restrict__ out,
                                                    int* __restrict__ bsum) {
    __shared__ int ws[4];
    int t = threadIdx.x;
    int base = blockIdx.x * 1024 + t * 4;
    int a0 = in[base], a1 = in[base + 1], a2 = in[base + 2], a3 = in[base + 3];
    int s = a0 + a1 + a2 + a3;
    int lane = t & 63, wid = t >> 6;
    int v = s;
#pragma unroll
    for (int d = 1; d < 64; d <<= 1) {
        int u = __shfl_up(v, d);
        if (lane >= d) v += u;
    }
    if (lane == 63) ws[wid] = v;
    __syncthreads();
    int wofs = 0;
    if (wid > 0) wofs += ws[0];
    if (wid > 1) wofs += ws[1];
    if (wid > 2) wofs += ws[2];
    int excl = wofs + v - s;
    out[base] = excl;
    out[base + 1] = excl + a0;
    out[base + 2] = excl + a0 + a1;
    out[base + 3] = excl + a0 + a1 + a2;
    if (t == 255) bsum[blockIdx.x] = wofs + v;
}

__global__ __launch_bounds__(64) void scan2_kernel(int* __restrict__ bsum, int nb) {
    int t = threadIdx.x;
    int orig = (t < nb) ? bsum[t] : 0;
    int v = orig;
#pragma unroll
    for (int d = 1; d < 64; d <<= 1) {
        int u = __shfl_up(v, d);
        if (t >= d) v += u;
    }
    if (t < nb) bsum[t] = v - orig;
}

__global__ __launch_bounds__(256) void scan3_kernel(int* __restrict__ out,
                                                    const int* __restrict__ bsum) {
    int base = blockIdx.x * 1024 + threadIdx.x * 4;
    int b = bsum[blockIdx.x];
    out[base] += b; out[base + 1] += b; out[base + 2] += b; out[base + 3] += b;
}

// ---------------- scatter edges into CSR order ----------------
__global__ __launch_bounds__(256) void scatter_edges_kernel(const int* __restrict__ src,
                                                            const int* __restrict__ dst,
                                                            int* __restrict__ cursor,
                                                            int* __restrict__ csr_nf,
                                                            int* __restrict__ csr_ef) {
    int e = blockIdx.x * 256 + threadIdx.x;
    if (e >= NE) return;
    int d = dst[e];
    int pos = atomicAdd(&cursor[d], 1);
    csr_nf[pos] = src[e];
    csr_ef[pos] = e;
}

// ---------------- gather-sum aggregation ----------------
template <int F>
__global__ __launch_bounds__(256) void agg_kernel(const float* __restrict__ table,
                                                  const int* __restrict__ rows,
                                                  const int* __restrict__ off,
                                                  float* __restrict__ out) {
    constexpr int C = F / 4;          // float4 chunks per row
    constexpr int NPW = 64 / C;       // nodes per wave
    int t = threadIdx.x;
    int lane = t & 63, wid = t >> 6;
    int sub = lane / C;
    int ch = lane - sub * C;
    int n = (blockIdx.x * 4 + wid) * NPW + sub;
    if (sub >= NPW || n >= NN) return;
    int s = off[n], e = off[n + 1];
    float ax0 = 0.f, ax1 = 0.f, ax2 = 0.f, ax3 = 0.f;
    float bx0 = 0.f, bx1 = 0.f, bx2 = 0.f, bx3 = 0.f;
    int i = s;
    for (; i + 1 < e; i += 2) {
        int r0 = rows[i], r1 = rows[i + 1];
        float4 v0 = *(const float4*)(table + (size_t)r0 * F + ch * 4);
        float4 v1 = *(const float4*)(table + (size_t)r1 * F + ch * 4);
        ax0 += v0.x; ax1 += v0.y; ax2 += v0.z; ax3 += v0.w;
        bx0 += v1.x; bx1 += v1.y; bx2 += v1.z; bx3 += v1.w;
    }
    if (i < e) {
        int r0 = rows[i];
        float4 v0 = *(const float4*)(table + (size_t)r0 * F + ch * 4);
        ax0 += v0.x; ax1 += v0.y; ax2 += v0.z; ax3 += v0.w;
    }
    float4 r;
    r.x = ax0 + bx0; r.y = ax1 + bx1; r.z = ax2 + bx2; r.w = ax3 + bx3;
    *(float4*)(out + (size_t)n * F + ch * 4) = r;
}

// ---------------- tiled SGEMM with fused epilogue ----------------
// out[M x NT] = concat(X1[MxK1], X2[MxK2]) @ W^T + epilogue
// MSG: (acc + deg*bias)/max(deg,1);  !MSG: relu(acc + bias)
// Tile 128(M) x 64(N), 256 threads, 8x4 per thread, K-step 16,
// register-prefetch pipeline (global loads for step s+1 issue before compute(s)).
template <int K1, int K2, int NT, bool MSG>
__global__ __launch_bounds__(256) void gemm_kernel(const float* __restrict__ X1,
                                                   const float* __restrict__ X2,
                                                   const float* __restrict__ W,
                                                   const float* __restrict__ bias,
                                                   const int* __restrict__ off,
                                                   float* __restrict__ out) {
    constexpr int KT = K1 + K2;
    constexpr int NKS = (KT + 15) / 16;   // ragged tail handled by zero guard loads
    __shared__ float Xs[16][132];         // stride 132 floats = 528B, 16B-aligned rows
    __shared__ float Ws[16][68];          // stride 68 floats = 272B, 16B-aligned rows

    const int t = threadIdx.x;
    const int m0 = blockIdx.x * 128;
    const int n0 = blockIdx.y * 64;

    // staging roles: X tile 128x16 -> 8 floats/thread; W tile 64x16 -> 4 floats/thread
    const int xm = t >> 1;                // 0..127 (row within tile)
    const int xh = (t & 1) * 8;           // k offset 0 or 8
    const int wn = t >> 2;                // 0..63
    const int wc = (t & 3) * 4;           // k offset 0,4,8,12

    // compute roles: thread = rows ty*8..+7, cols tx*4..+3
    const int tx = t & 15;
    const int ty = t >> 4;

    const int xrow = m0 + xm;
    const bool xok = xrow < NN;
    const bool wok = (n0 + wn) < NT;
    const float* __restrict__ xrp1 = X1 + (size_t)xrow * K1;
    const float* __restrict__ xrp2 = X2 + (size_t)xrow * K2;
    const float* __restrict__ wrp  = W + (size_t)(n0 + wn) * KT;

    float acc[8][4] = {};
    float4 rx0, rx1, rw;

    auto loadT = [&](int k0) {
        // K1 % 8 == 0 for all instantiations -> the 8-float chunk never straddles
        // the X1|X2 seam. KT % 8 == 0 -> guard covers the full chunk.
        const int kv = k0 + xh;
        rx0 = make_float4(0.f, 0.f, 0.f, 0.f);
        rx1 = rx0;
        if (xok && kv < KT) {
            const float* p = (kv < K1) ? (xrp1 + kv) : (xrp2 + (kv - K1));
            rx0 = *(const float4*)p;
            rx1 = *(const float4*)(p + 4);
        }
        rw = make_float4(0.f, 0.f, 0.f, 0.f);
        const int kw = k0 + wc;
        if (wok && kw < KT) rw = *(const float4*)(wrp + kw);
    };
    auto storeT = [&]() {
        Xs[xh + 0][xm] = rx0.x; Xs[xh + 1][xm] = rx0.y;
        Xs[xh + 2][xm] = rx0.z; Xs[xh + 3][xm] = rx0.w;
        Xs[xh + 4][xm] = rx1.x; Xs[xh + 5][xm] = rx1.y;
        Xs[xh + 6][xm] = rx1.z; Xs[xh + 7][xm] = rx1.w;
        Ws[wc + 0][wn] = rw.x;  Ws[wc + 1][wn] = rw.y;
        Ws[wc + 2][wn] = rw.z;  Ws[wc + 3][wn] = rw.w;
    };

    loadT(0);
    storeT();
    __syncthreads();

    for (int s = 0; s < NKS; ++s) {
        const bool more = (s + 1 < NKS);
        if (more) loadT((s + 1) * 16);    // issue early; drains under compute
#pragma unroll
        for (int k = 0; k < 16; ++k) {
            const float4 xa = *(const float4*)&Xs[k][ty * 8];
            const float4 xb = *(const float4*)&Xs[k][ty * 8 + 4];
            const float4 wv = *(const float4*)&Ws[k][tx * 4];
            const float xv[8] = {xa.x, xa.y, xa.z, xa.w, xb.x, xb.y, xb.z, xb.w};
#pragma unroll
            for (int i = 0; i < 8; ++i) {
                acc[i][0] += xv[i] * wv.x;
                acc[i][1] += xv[i] * wv.y;
                acc[i][2] += xv[i] * wv.z;
                acc[i][3] += xv[i] * wv.w;
            }
        }
        if (more) {
            __syncthreads();
            storeT();
            __syncthreads();
        }
    }

    const int o0 = n0 + tx * 4;
    if (o0 >= NT) return;
    const float4 bv = *(const float4*)(bias + o0);
#pragma unroll
    for (int i = 0; i < 8; ++i) {
        const int n = m0 + ty * 8 + i;
        if (n >= NN) break;
        float4 r;
        if (MSG) {
            float d = (float)(off[n + 1] - off[n]);
            float inv = 1.0f / fmaxf(d, 1.0f);
            r.x = (acc[i][0] + d * bv.x) * inv;
            r.y = (acc[i][1] + d * bv.y) * inv;
            r.z = (acc[i][2] + d * bv.z) * inv;
            r.w = (acc[i][3] + d * bv.w) * inv;
        } else {
            r.x = fmaxf(acc[i][0] + bv.x, 0.0f);
            r.y = fmaxf(acc[i][1] + bv.y, 0.0f);
            r.z = fmaxf(acc[i][2] + bv.z, 0.0f);
            r.w = fmaxf(acc[i][3] + bv.w, 0.0f);
        }
        *(float4*)(out + (size_t)n * NT + o0) = r;
    }
}

extern "C" void kernel_launch(void* const* d_in, const int* in_sizes, int n_in,
                              void* d_out, int out_size, void* d_ws, size_t ws_size,
                              hipStream_t stream) {
    const float* nfeats = (const float*)d_in[0];
    const float* efeats = (const float*)d_in[1];
    const float* Wm1 = (const float*)d_in[2];
    const float* bm1 = (const float*)d_in[3];
    const float* Wa1 = (const float*)d_in[4];
    const float* ba1 = (const float*)d_in[5];
    const float* Wm2 = (const float*)d_in[6];
    const float* bm2 = (const float*)d_in[7];
    const float* Wa2 = (const float*)d_in[8];
    const float* ba2 = (const float*)d_in[9];
    const float* Wm3 = (const float*)d_in[10];
    const float* bm3 = (const float*)d_in[11];
    const float* Wa3 = (const float*)d_in[12];
    const float* ba3 = (const float*)d_in[13];
    const int* src = (const int*)d_in[14];
    const int* dst = (const int*)d_in[15];
    float* out = (float*)d_out;

    // workspace layout (4-byte units)
    int* iws = (int*)d_ws;
    int* ideg   = iws;                  // PADN
    int* off    = iws + PADN;           // PADN
    int* cursor = iws + 2 * PADN;       // PADN
    int* csr_nf = iws + 3 * PADN;       // NE
    int* csr_ef = csr_nf + NE;          // NE
    float* B = (float*)(csr_ef + NE);   // NN*64  = 3,200,000
    float* P = B + 3200000;             // NN*152 = 7,600,000
    float* Q = P + 7600000;             // NN*152
    float* R = Q + 7600000;             // NN*152

    const int BLK = 256;
    auto cdiv = [](long long a, long long b) { return (int)((a + b - 1) / b); };
    dim3 g152(cdiv(NN, 128), cdiv(152, 64));   // 391 x 3
    dim3 g64(cdiv(NN, 128), 1);                // 391 x 1
    const int NB = PADN / 1024;  // 49

    // ---- CSR build ----
    hipMemsetAsync(ideg, 0, (size_t)PADN * 4, stream);
    hist_kernel<<<cdiv(NE, BLK), BLK, 0, stream>>>(dst, ideg);
    scan1_kernel<<<NB, 256, 0, stream>>>(ideg, off, cursor);
    scan2_kernel<<<1, 64, 0, stream>>>(cursor, NB);
    scan3_kernel<<<NB, 256, 0, stream>>>(off, cursor);
    hipMemcpyAsync(cursor, off, (size_t)NN * 4, hipMemcpyDeviceToDevice, stream);
    scatter_edges_kernel<<<cdiv(NE, BLK), BLK, 0, stream>>>(src, dst, cursor, csr_nf, csr_ef);

    // ---- layer-invariant: B = segsum(ef) ----
    agg_kernel<EDIM_><<<cdiv(NN, 16), BLK, 0, stream>>>(efeats, csr_ef, off, B);

    // ---- layer 1 ----
    agg_kernel<NIN><<<cdiv(NN, 16), BLK, 0, stream>>>(nfeats, csr_nf, off, P);
    gemm_kernel<NIN, EDIM_, HID_, true><<<g152, BLK, 0, stream>>>(P, B, Wm1, bm1, off, Q);
    gemm_kernel<NIN, HID_, HID_, false><<<g152, BLK, 0, stream>>>(nfeats, Q, Wa1, ba1, off, R);  // h1 = R

    // ---- layer 2 ----
    agg_kernel<HID_><<<cdiv(NN, 4), BLK, 0, stream>>>(R, csr_nf, off, P);
    gemm_kernel<HID_, EDIM_, HID_, true><<<g152, BLK, 0, stream>>>(P, B, Wm2, bm2, off, Q);
    gemm_kernel<HID_, HID_, HID_, false><<<g152, BLK, 0, stream>>>(R, Q, Wa2, ba2, off, P);      // h2 = P

    // ---- layer 3 ----
    agg_kernel<HID_><<<cdiv(NN, 4), BLK, 0, stream>>>(P, csr_nf, off, Q);
    gemm_kernel<HID_, EDIM_, NOUT, true><<<g64, BLK, 0, stream>>>(Q, B, Wm3, bm3, off, R);       // hn3 = R
    gemm_kernel<HID_, NOUT, NOUT, false><<<g64, BLK, 0, stream>>>(P, R, Wa3, ba3, off, out);
}

// Round 3
// 824.591 us; speedup vs baseline: 1.2137x; 1.2137x over previous
//
#include <hip/hip_runtime.h>

// GraphSAGE 3-layer, fp32.
// Linearity: segsum(Wm@concat(nf[src],ef)) == Wm_n@segsum(nf[src]) + Wm_e@segsum(ef) + deg*bm
// R3: on-device CSR + atomic-free gather aggregations (912 us).
// R4/R5: fp32 VALU GEMM 8x4-frag rewrite -> REGRESSED (31 TF, VGPR=136 over the
// 128 occupancy tier, ~3 waves/CU, VALUBusy 32%). fp32 vector path is stall-bound.
// R6 (this): fp16x2 split MFMA GEMM (Ootomo 3-product: hihi+hilo+lohi) on the
// 2.5 PF matrix pipe, ~830 TF effective ceiling. 128x64 tile, 4 waves x (64x32),
// mfma_f32_16x16x32_f16, K-step 32, 24KB LDS, reg-prefetch. X split in staging;
// W pre-split to padded hi/lo fp16 (+0.8 MB ws). Per-segment K pad to 32 (zeros).

#define NN 50000
#define NE 800000
#define NIN 64
#define EDIM_ 64
#define HID_ 152
#define NOUT 64
#define PADN 50176   // 49 * 1024, scan-friendly padding of NN

typedef float f4v __attribute__((ext_vector_type(4)));
typedef _Float16 h8v __attribute__((ext_vector_type(8)));
typedef _Float16 h4v __attribute__((ext_vector_type(4)));

// ---------------- histogram: integer in-degree ----------------
__global__ __launch_bounds__(256) void hist_kernel(const int* __restrict__ dst,
                                                   int* __restrict__ ideg) {
    int e = blockIdx.x * 256 + threadIdx.x;
    if (e < NE) atomicAdd(&ideg[dst[e]], 1);
}

// ---------------- exclusive scan, 3 kernels ----------------
__global__ __launch_bounds__(256) void scan1_kernel(const int* __restrict__ in,
                                                    int* __restrict__ out,
                                                    int* __restrict__ bsum) {
    __shared__ int ws[4];
    int t = threadIdx.x;
    int base = blockIdx.x * 1024 + t * 4;
    int a0 = in[base], a1 = in[base + 1], a2 = in[base + 2], a3 = in[base + 3];
    int s = a0 + a1 + a2 + a3;
    int lane = t & 63, wid = t >> 6;
    int v = s;
#pragma unroll
    for (int d = 1; d < 64; d <<= 1) {
        int u = __shfl_up(v, d);
        if (lane >= d) v += u;
    }
    if (lane == 63) ws[wid] = v;
    __syncthreads();
    int wofs = 0;
    if (wid > 0) wofs += ws[0];
    if (wid > 1) wofs += ws[1];
    if (wid > 2) wofs += ws[2];
    int excl = wofs + v - s;
    out[base] = excl;
    out[base + 1] = excl + a0;
    out[base + 2] = excl + a0 + a1;
    out[base + 3] = excl + a0 + a1 + a2;
    if (t == 255) bsum[blockIdx.x] = wofs + v;
}

__global__ __launch_bounds__(64) void scan2_kernel(int* __restrict__ bsum, int nb) {
    int t = threadIdx.x;
    int orig = (t < nb) ? bsum[t] : 0;
    int v = orig;
#pragma unroll
    for (int d = 1; d < 64; d <<= 1) {
        int u = __shfl_up(v, d);
        if (t >= d) v += u;
    }
    if (t < nb) bsum[t] = v - orig;
}

__global__ __launch_bounds__(256) void scan3_kernel(int* __restrict__ out,
                                                    const int* __restrict__ bsum) {
    int base = blockIdx.x * 1024 + threadIdx.x * 4;
    int b = bsum[blockIdx.x];
    out[base] += b; out[base + 1] += b; out[base + 2] += b; out[base + 3] += b;
}

// ---------------- scatter edges into CSR order ----------------
__global__ __launch_bounds__(256) void scatter_edges_kernel(const int* __restrict__ src,
                                                            const int* __restrict__ dst,
                                                            int* __restrict__ cursor,
                                                            int* __restrict__ csr_nf,
                                                            int* __restrict__ csr_ef) {
    int e = blockIdx.x * 256 + threadIdx.x;
    if (e >= NE) return;
    int d = dst[e];
    int pos = atomicAdd(&cursor[d], 1);
    csr_nf[pos] = src[e];
    csr_ef[pos] = e;
}

// ---------------- gather-sum aggregation ----------------
template <int F>
__global__ __launch_bounds__(256) void agg_kernel(const float* __restrict__ table,
                                                  const int* __restrict__ rows,
                                                  const int* __restrict__ off,
                                                  float* __restrict__ out) {
    constexpr int C = F / 4;          // float4 chunks per row
    constexpr int NPW = 64 / C;       // nodes per wave
    int t = threadIdx.x;
    int lane = t & 63, wid = t >> 6;
    int sub = lane / C;
    int ch = lane - sub * C;
    int n = (blockIdx.x * 4 + wid) * NPW + sub;
    if (sub >= NPW || n >= NN) return;
    int s = off[n], e = off[n + 1];
    float ax0 = 0.f, ax1 = 0.f, ax2 = 0.f, ax3 = 0.f;
    float bx0 = 0.f, bx1 = 0.f, bx2 = 0.f, bx3 = 0.f;
    int i = s;
    for (; i + 1 < e; i += 2) {
        int r0 = rows[i], r1 = rows[i + 1];
        float4 v0 = *(const float4*)(table + (size_t)r0 * F + ch * 4);
        float4 v1 = *(const float4*)(table + (size_t)r1 * F + ch * 4);
        ax0 += v0.x; ax1 += v0.y; ax2 += v0.z; ax3 += v0.w;
        bx0 += v1.x; bx1 += v1.y; bx2 += v1.z; bx3 += v1.w;
    }
    if (i < e) {
        int r0 = rows[i];
        float4 v0 = *(const float4*)(table + (size_t)r0 * F + ch * 4);
        ax0 += v0.x; ax1 += v0.y; ax2 += v0.z; ax3 += v0.w;
    }
    float4 r;
    r.x = ax0 + bx0; r.y = ax1 + bx1; r.z = ax2 + bx2; r.w = ax3 + bx3;
    *(float4*)(out + (size_t)n * F + ch * 4) = r;
}

// ---------------- W pre-split: fp32 -> padded hi/lo fp16 ----------------
// Output [NPAD][KTP], layout [n][k]; k<K1P maps to W cols 0..Kin1-1 (zero pad),
// k>=K1P maps to W cols Kin1..Kin1+Kin2-1 (zero pad). n>=NT rows are zero.
__global__ __launch_bounds__(256) void wsplit_kernel(const float* __restrict__ W,
                                                     _Float16* __restrict__ hi,
                                                     _Float16* __restrict__ lo,
                                                     int NT, int Kin1, int K1P,
                                                     int Kin2, int KTP, int total) {
    int e = blockIdx.x * 256 + threadIdx.x;
    if (e >= total) return;
    int n = e / KTP, k = e - n * KTP;
    float v = 0.f;
    if (n < NT) {
        int s = -1;
        if (k < K1P) { if (k < Kin1) s = k; }
        else { int k2 = k - K1P; if (k2 < Kin2) s = Kin1 + k2; }
        if (s >= 0) v = W[(size_t)n * (Kin1 + Kin2) + s];
    }
    _Float16 h = (_Float16)v;
    hi[e] = h;
    lo[e] = (_Float16)(v - (float)h);
}

// ---------------- fp16x2-split MFMA GEMM with fused epilogue ----------------
// out[M x NT] = concat(X1[MxK1], X2[MxK2]) @ W^T + epilogue, via 3-product split.
// Block tile 128(M) x 64(N), 4 waves of 64x32, mfma_f32_16x16x32_f16, K-step 32.
// LDS: Ahi[128][32] | Alo[128][32] | Bhi[64][32] | Blo[64][32] fp16 = 24 KB.
// MSG: (acc + deg*bias)/max(deg,1);  !MSG: relu(acc + bias).
template <int K1P, int K2P, int K1, int K2, int NT, bool MSG>
__global__ __launch_bounds__(256) void mgemm_kernel(const float* __restrict__ X1,
                                                    const float* __restrict__ X2,
                                                    const _Float16* __restrict__ Whi,
                                                    const _Float16* __restrict__ Wlo,
                                                    const float* __restrict__ bias,
                                                    const int* __restrict__ off,
                                                    float* __restrict__ out) {
    constexpr int KTP = K1P + K2P;     // multiple of 32
    constexpr int NKS = KTP / 32;
    __shared__ _Float16 sm[12288];     // Ahi 0 | Alo 4096 | Bhi 8192 | Blo 10240 (halves)

    const int t = threadIdx.x;
    const int m0 = blockIdx.x * 128;
    const int n0 = blockIdx.y * 64;

    // ---- staging geometry ----
    // A: 128 rows x 8 float4-chunks = 1024 chunks; thread t handles chunks t+256*i.
    //    row = (t>>3)+32*i, k-offset = (t&7)*4.  (all Ks are multiples of 4)
    // B: 64 rows x 4 h8-chunks per plane; chunk i=0 -> hi plane, i=1 -> lo plane.
    //    row = t>>2, k-offset = (t&3)*8.  W arrays are padded -> no guards.
    const int ar = t >> 3;
    const int akc = (t & 7) * 4;
    const int br = t >> 2;
    const int bkc = (t & 3) * 8;
    const _Float16* wph = Whi + (size_t)(n0 + br) * KTP + bkc;
    const _Float16* wpl = Wlo + (size_t)(n0 + br) * KTP + bkc;

    f4v ax[4];
    h8v bxh, bxl;

    auto loadT = [&](int k0) {
        const float* Xp; int Ka, kb;
        if (k0 < K1P) { Xp = X1; Ka = K1; kb = k0; }
        else          { Xp = X2; Ka = K2; kb = k0 - K1P; }
        const int kg = kb + akc;
        const bool kok = kg < Ka;      // chunk 4-aligned, Ka%4==0 -> whole chunk valid
        f4v z = {0.f, 0.f, 0.f, 0.f};
#pragma unroll
        for (int i = 0; i < 4; ++i) {
            const int row = m0 + ar + 32 * i;
            ax[i] = (kok && row < NN) ? *(const f4v*)(Xp + (size_t)row * Ka + kg) : z;
        }
        bxh = *(const h8v*)(wph + k0);
        bxl = *(const h8v*)(wpl + k0);
    };
    auto storeT = [&]() {
#pragma unroll
        for (int i = 0; i < 4; ++i) {
            h4v hi, lo;
#pragma unroll
            for (int j = 0; j < 4; ++j) {
                float v = ax[i][j];
                _Float16 h = (_Float16)v;
                hi[j] = h;
                lo[j] = (_Float16)(v - (float)h);
            }
            const int d = (ar + 32 * i) * 32 + akc;
            *(h4v*)(sm + d) = hi;
            *(h4v*)(sm + 4096 + d) = lo;
        }
        const int bd = br * 32 + bkc;
        *(h8v*)(sm + 8192 + bd) = bxh;
        *(h8v*)(sm + 10240 + bd) = bxl;
    };

    // ---- compute geometry: wave wid at (wm,wn) of 2x2; wave tile 64(M)x32(N) ----
    const int lane = t & 63, wid = t >> 6;
    const int wm = wid >> 1, wn = wid & 1;
    const int lr = lane & 15, g = lane >> 4;
    const int aoff = (wm * 64 + lr) * 32 + g * 8;   // + mf*512 (16 rows)
    const int boff = (wn * 32 + lr) * 32 + g * 8;   // + nf*512

    f4v acc[4][2] = {};

    loadT(0);
    storeT();
    __syncthreads();

    for (int s = 0; s < NKS; ++s) {
        const bool more = (s + 1 < NKS);
        if (more) loadT((s + 1) * 32);   // issue early; drains under MFMA
        h8v ah[4], al[4], bh[2], bl[2];
#pragma unroll
        for (int mf = 0; mf < 4; ++mf) {
            ah[mf] = *(const h8v*)(sm + aoff + mf * 512);
            al[mf] = *(const h8v*)(sm + 4096 + aoff + mf * 512);
        }
#pragma unroll
        for (int nf = 0; nf < 2; ++nf) {
            bh[nf] = *(const h8v*)(sm + 8192 + boff + nf * 512);
            bl[nf] = *(const h8v*)(sm + 10240 + boff + nf * 512);
        }
#pragma unroll
        for (int mf = 0; mf < 4; ++mf)
#pragma unroll
            for (int nf = 0; nf < 2; ++nf) {
                acc[mf][nf] = __builtin_amdgcn_mfma_f32_16x16x32_f16(ah[mf], bh[nf], acc[mf][nf], 0, 0, 0);
                acc[mf][nf] = __builtin_amdgcn_mfma_f32_16x16x32_f16(ah[mf], bl[nf], acc[mf][nf], 0, 0, 0);
                acc[mf][nf] = __builtin_amdgcn_mfma_f32_16x16x32_f16(al[mf], bh[nf], acc[mf][nf], 0, 0, 0);
            }
        if (more) {
            __syncthreads();
            storeT();
            __syncthreads();
        }
    }

    // ---- epilogue (C layout: col = lane&15, row = (lane>>4)*4 + reg; m89) ----
#pragma unroll
    for (int mf = 0; mf < 4; ++mf) {
#pragma unroll
        for (int r = 0; r < 4; ++r) {
            const int m = m0 + wm * 64 + mf * 16 + g * 4 + r;
            if (m >= NN) continue;
            float dv = 0.f, inv = 0.f;
            if (MSG) {
                dv = (float)(off[m + 1] - off[m]);
                inv = 1.0f / fmaxf(dv, 1.0f);
            }
#pragma unroll
            for (int nf = 0; nf < 2; ++nf) {
                const int n = n0 + wn * 32 + nf * 16 + lr;
                if (n >= NT) continue;
                const float a = acc[mf][nf][r];
                const float val = MSG ? (a + dv * bias[n]) * inv
                                      : fmaxf(a + bias[n], 0.0f);
                out[(size_t)m * NT + n] = val;
            }
        }
    }
}

extern "C" void kernel_launch(void* const* d_in, const int* in_sizes, int n_in,
                              void* d_out, int out_size, void* d_ws, size_t ws_size,
                              hipStream_t stream) {
    const float* nfeats = (const float*)d_in[0];
    const float* efeats = (const float*)d_in[1];
    const float* Wm1 = (const float*)d_in[2];
    const float* bm1 = (const float*)d_in[3];
    const float* Wa1 = (const float*)d_in[4];
    const float* ba1 = (const float*)d_in[5];
    const float* Wm2 = (const float*)d_in[6];
    const float* bm2 = (const float*)d_in[7];
    const float* Wa2 = (const float*)d_in[8];
    const float* ba2 = (const float*)d_in[9];
    const float* Wm3 = (const float*)d_in[10];
    const float* bm3 = (const float*)d_in[11];
    const float* Wa3 = (const float*)d_in[12];
    const float* ba3 = (const float*)d_in[13];
    const int* src = (const int*)d_in[14];
    const int* dst = (const int*)d_in[15];
    float* out = (float*)d_out;

    // workspace layout (4-byte units)
    int* iws = (int*)d_ws;
    int* ideg   = iws;                  // PADN
    int* off    = iws + PADN;           // PADN
    int* cursor = iws + 2 * PADN;       // PADN
    int* csr_nf = iws + 3 * PADN;       // NE
    int* csr_ef = csr_nf + NE;          // NE
    float* B = (float*)(csr_ef + NE);   // NN*64  = 3,200,000
    float* P = B + 3200000;             // NN*152 = 7,600,000
    float* Q = P + 7600000;             // NN*152
    float* R = Q + 7600000;             // NN*152
    // split weights (halves), ~0.8 MB appended after R
    _Float16* w1h = (_Float16*)(R + 7600000);
    _Float16* w1l = w1h + 24576;        // 192*128
    _Float16* w2h = w1l + 24576;
    _Float16* w2l = w2h + 43008;        // 192*224
    _Float16* w3h = w2l + 43008;
    _Float16* w3l = w3h + 43008;        // 192*224
    _Float16* w4h = w3l + 43008;
    _Float16* w4l = w4h + 61440;        // 192*320
    _Float16* w5h = w4l + 61440;
    _Float16* w5l = w5h + 14336;        // 64*224
    _Float16* w6h = w5l + 14336;
    _Float16* w6l = w6h + 14336;        // 64*224

    const int BLK = 256;
    auto cdiv = [](long long a, long long b) { return (int)((a + b - 1) / b); };
    dim3 g152(cdiv(NN, 128), 3);   // N pad 192
    dim3 g64(cdiv(NN, 128), 1);
    const int NB = PADN / 1024;  // 49

    // ---- split weights (independent of graph data) ----
    wsplit_kernel<<<96,  BLK, 0, stream>>>(Wm1, w1h, w1l, 152, 64, 64, 64, 128, 24576);
    wsplit_kernel<<<168, BLK, 0, stream>>>(Wa1, w2h, w2l, 152, 64, 64, 152, 224, 43008);
    wsplit_kernel<<<168, BLK, 0, stream>>>(Wm2, w3h, w3l, 152, 152, 160, 64, 224, 43008);
    wsplit_kernel<<<240, BLK, 0, stream>>>(Wa2, w4h, w4l, 152, 152, 160, 152, 320, 61440);
    wsplit_kernel<<<56,  BLK, 0, stream>>>(Wm3, w5h, w5l, 64, 152, 160, 64, 224, 14336);
    wsplit_kernel<<<56,  BLK, 0, stream>>>(Wa3, w6h, w6l, 64, 152, 160, 64, 224, 14336);

    // ---- CSR build ----
    hipMemsetAsync(ideg, 0, (size_t)PADN * 4, stream);
    hist_kernel<<<cdiv(NE, BLK), BLK, 0, stream>>>(dst, ideg);
    scan1_kernel<<<NB, 256, 0, stream>>>(ideg, off, cursor);
    scan2_kernel<<<1, 64, 0, stream>>>(cursor, NB);
    scan3_kernel<<<NB, 256, 0, stream>>>(off, cursor);
    hipMemcpyAsync(cursor, off, (size_t)NN * 4, hipMemcpyDeviceToDevice, stream);
    scatter_edges_kernel<<<cdiv(NE, BLK), BLK, 0, stream>>>(src, dst, cursor, csr_nf, csr_ef);

    // ---- layer-invariant: B = segsum(ef) ----
    agg_kernel<EDIM_><<<cdiv(NN, 16), BLK, 0, stream>>>(efeats, csr_ef, off, B);

    // ---- layer 1 ----
    agg_kernel<NIN><<<cdiv(NN, 16), BLK, 0, stream>>>(nfeats, csr_nf, off, P);
    mgemm_kernel<64, 64, 64, 64, HID_, true><<<g152, BLK, 0, stream>>>(P, B, w1h, w1l, bm1, off, Q);
    mgemm_kernel<64, 160, 64, 152, HID_, false><<<g152, BLK, 0, stream>>>(nfeats, Q, w2h, w2l, ba1, off, R);  // h1 = R

    // ---- layer 2 ----
    agg_kernel<HID_><<<cdiv(NN, 4), BLK, 0, stream>>>(R, csr_nf, off, P);
    mgemm_kernel<160, 64, 152, 64, HID_, true><<<g152, BLK, 0, stream>>>(P, B, w3h, w3l, bm2, off, Q);
    mgemm_kernel<160, 160, 152, 152, HID_, false><<<g152, BLK, 0, stream>>>(R, Q, w4h, w4l, ba2, off, P);     // h2 = P

    // ---- layer 3 ----
    agg_kernel<HID_><<<cdiv(NN, 4), BLK, 0, stream>>>(P, csr_nf, off, Q);
    mgemm_kernel<160, 64, 152, 64, NOUT, true><<<g64, BLK, 0, stream>>>(Q, B, w5h, w5l, bm3, off, R);         // hn3 = R
    mgemm_kernel<160, 64, 152, 64, NOUT, false><<<g64, BLK, 0, stream>>>(P, R, w6h, w6l, ba3, off, out);
}